// Round 9
// baseline (962.841 us; speedup 1.0000x reference)
//
#include <hip/hip_runtime.h>
#include <stdint.h>

#define GAS __attribute__((address_space(1)))
#define LAS __attribute__((address_space(3)))

typedef int v4i __attribute__((ext_vector_type(4)));

constexpr int Mdim = 8192;    // B*S = 4*2048
constexpr int Ndim = 16384;   // D_OUT
constexpr int Kdim = 4096;    // D_IN

__device__ __forceinline__ int pack4i8(int a, int b, int c, int d) {
    return (a & 255) | ((b & 255) << 8) | ((c & 255) << 16) | ((d & 255) << 24);
}

__device__ __forceinline__ int qz(float v, float inv) {
    return (int)fminf(fmaxf(rintf(v * inv), -128.0f), 127.0f);
}

// ---- pass 1: quantize x fp32 -> int8 (16 elems/thread) ----
__global__ void k_quant_x(const float* __restrict__ x, const float* __restrict__ asc,
                          int8_t* __restrict__ xq) {
    const int i = blockIdx.x * blockDim.x + threadIdx.x;
    const float inv = 1.0f / *asc;
    const float4* xv = (const float4*)x + (size_t)i * 4;
    float4 f0 = xv[0], f1 = xv[1], f2 = xv[2], f3 = xv[3];
    int4 o;
    o.x = pack4i8(qz(f0.x, inv), qz(f0.y, inv), qz(f0.z, inv), qz(f0.w, inv));
    o.y = pack4i8(qz(f1.x, inv), qz(f1.y, inv), qz(f1.z, inv), qz(f1.w, inv));
    o.z = pack4i8(qz(f2.x, inv), qz(f2.y, inv), qz(f2.z, inv), qz(f2.w, inv));
    o.w = pack4i8(qz(f3.x, inv), qz(f3.y, inv), qz(f3.z, inv), qz(f3.w, inv));
    ((int4*)xq)[i] = o;
}

// ---- pass 2: pack weights into FRAGMENT-LINEAR layout ----
// chunk id c = ((ntile*64 + kstep)*64 + lane); lane l -> n = ntile*16 + (l&15),
// k = kstep*64 + (l>>4)*16. GEMM B-frag load becomes one contiguous 1 KB
// wave read. Each thread reads 16 int32 (64B, one full cache line).
__global__ void k_pack_w(const int* __restrict__ w, int8_t* __restrict__ wp) {
    const int c = blockIdx.x * blockDim.x + threadIdx.x;
    const int l = c & 63, ks = (c >> 6) & 63, nt = c >> 12;
    const int n = nt * 16 + (l & 15);
    const int k = (ks << 6) + ((l >> 4) << 4);
    const int4* src = (const int4*)(w + (size_t)n * Kdim + k);
    int4 a = src[0], b = src[1], cc = src[2], d = src[3];
    int4 o;
    o.x = pack4i8(a.x, a.y, a.z, a.w);
    o.y = pack4i8(b.x, b.y, b.z, b.w);
    o.z = pack4i8(cc.x, cc.y, cc.z, cc.w);
    o.w = pack4i8(d.x, d.y, d.z, d.w);
    ((int4*)wp)[c] = o;
}

// ============================================================================
// pass 3 (main): 256(M) x 128(N) block, 4 waves (2M x 2N), wave tile 128x64.
//   - B: packed fragment-linear -> one contiguous 1KB global load per frag,
//     double-buffered in regs (bP/bQ). NEVER in LDS.
//   - A: LDS 4-slot ring (4 x 16KB = 64 KiB) -> 2 blocks/CU (independent
//     barrier domains; de-phased MFMA/LDS overlap, m114).
//   - per step T: vmcnt(8); s_barrier; loadB(T+1); stageA(T+2); 8x ds_read
//     A(T); 32 MFMA with B(T) regs (compiler counted-lgkm interleave).
//   - vmcnt ledger: in-flight at T = stA(T)[T-2](4) + B(T)[T-1](4) +
//     stA(T+1)[T-1](4) -> vmcnt(8) retires exactly stA(T). Tail T=63: (4).
//     Slot hazard: write slot (T+2)&3; its readers (step T-2) completed
//     before barrier(T-1) -- two barriers upstream of the write issue.
//   - A swizzle/staging byte-identical to rounds 2-7 (0 bank conflicts).
//   - LDS/CU/step ~750 cy < MFMA 1306 cy -> MFMA-bound regime (first time).
// ============================================================================
#define VMW(N) asm volatile("s_waitcnt vmcnt(" #N ")" ::: "memory")

#define STEP(T, BC, BN, LB, SA, VMN)                                         \
  {                                                                          \
    VMW(VMN);                                                                \
    __builtin_amdgcn_s_barrier();                                            \
    __builtin_amdgcn_sched_barrier(0);                                       \
    if (LB) {                                                                \
      _Pragma("unroll") for (int f = 0; f < 4; ++f)                          \
        BN[f] = *(const v4i*)(Bp + ((((size_t)(ntb + f)) << 6 | ((T) + 1))   \
                                    << 10) + (lane << 4));                   \
    }                                                                        \
    if (SA) stA((T) + 2);                                                    \
    {                                                                        \
      const int8_t* S_ = lds + (((T) & 3) << 14);                            \
      v4i a_[8];                                                             \
      _Pragma("unroll") for (int f = 0; f < 8; ++f)                          \
        a_[f] = *(const v4i*)(S_ + aoff + f * 1024);                         \
      __builtin_amdgcn_s_setprio(1);                                         \
      _Pragma("unroll") for (int fi = 0; fi < 8; ++fi)                       \
        _Pragma("unroll") for (int fj = 0; fj < 4; ++fj)                     \
          acc[fi][fj] = __builtin_amdgcn_mfma_i32_16x16x64_i8(               \
              a_[fi], BC[fj], acc[fi][fj], 0, 0, 0);                         \
      __builtin_amdgcn_s_setprio(0);                                         \
    }                                                                        \
  }

__global__ __launch_bounds__(256, 2)
void k_gemm_bp(const int8_t* __restrict__ Aq, const int8_t* __restrict__ Bp,
               const float* __restrict__ wscale, const float* __restrict__ asc,
               const float* __restrict__ bias, float* __restrict__ out) {
    __shared__ __align__(16) int8_t lds[65536];   // 4 slots x 16KB, A only
    const int tid = threadIdx.x, lane = tid & 63, w = tid >> 6;
    const int wm = w >> 1, wn = w & 1;              // 2M x 2N wave grid
    const int lrow = lane & 15, kgrp = lane >> 4;

    const int bid = blockIdx.x;                     // grid = 4096, %8 == 0
    const int swz = ((bid & 7) << 9) | (bid >> 3);  // bijective XCD swizzle
    const int mt = swz & 31, nt = swz >> 5;         // m fastest: share B panel
    const int m0 = mt << 8, n0 = nt << 7;

    // ---- A staging: 4 units x 4KB (64 rows x 64B) per 16KB step-slot.
    // dest linear tid*16; source col inverse-swizzled (verified 0-conflict).
    const int srow = tid >> 2;                      // 0..63
    const int scol = (((tid & 3) ^ ((tid >> 3) & 3)) << 4);
    const int8_t* gA[4];
#pragma unroll
    for (int u = 0; u < 4; ++u)
        gA[u] = Aq + (size_t)(m0 + u * 64 + srow) * Kdim + scol;
    const int dstoff = w << 10;                     // + HW lane*16

    auto stA = [&](int t) {
        int8_t* base = lds + ((t & 3) << 14) + dstoff;
        const int kb = t << 6;
#pragma unroll
        for (int u = 0; u < 4; ++u)
            __builtin_amdgcn_global_load_lds((const GAS void*)(gA[u] + kb),
                                             (LAS void*)(base + u * 4096), 16, 0, 0);
    };

    // ---- B packed fragment base: wave's 4 n-tiles ----
    const int ntb = (n0 >> 4) + (wn << 2);

    // ---- A read addressing (verified conflict-free swizzle) ----
    const int kc = (kgrp ^ ((lrow >> 1) & 3)) << 4;
    const int aoff = ((wm << 7) + lrow) * 64 + kc;

    v4i acc[8][4];
#pragma unroll
    for (int i = 0; i < 8; ++i)
#pragma unroll
        for (int j = 0; j < 4; ++j) acc[i][j] = (v4i){0, 0, 0, 0};

    v4i bP[4], bQ[4];

    // prologue: stage A tiles 0,1; load B(0)
    stA(0); stA(1);
#pragma unroll
    for (int f = 0; f < 4; ++f)
        bP[f] = *(const v4i*)(Bp + ((((size_t)(ntb + f)) << 6) << 10) + (lane << 4));

    for (int j = 0; j < 15; ++j) {
        const int t = j << 2;
        STEP(t + 0, bP, bQ, 1, 1, 8)
        STEP(t + 1, bQ, bP, 1, 1, 8)
        STEP(t + 2, bP, bQ, 1, 1, 8)
        STEP(t + 3, bQ, bP, 1, 1, 8)
    }
    // peeled last iter: t = 60..63
    STEP(60, bP, bQ, 1, 1, 8)   // stages A(62)
    STEP(61, bQ, bP, 1, 1, 8)   // stages A(63)
    STEP(62, bP, bQ, 1, 0, 8)   // loads B(63), no stage
    STEP(63, bQ, bP, 0, 0, 4)   // in-flight: stA(63)+B(63) -> vmcnt(4)

    // epilogue: y = i32 * (act_scale * wscale[n]) + bias[n]
    const float ascale = *asc;
#pragma unroll
    for (int fj = 0; fj < 4; ++fj) {
        const int col = n0 + (wn << 6) + fj * 16 + lrow;
        const float sc = ascale * wscale[col];
        const float bb = bias[col];
#pragma unroll
        for (int mi = 0; mi < 8; ++mi) {
            const int r0 = m0 + (wm << 7) + mi * 16 + (kgrp << 2);
            float* o = out + (size_t)r0 * Ndim + col;
#pragma unroll
            for (int q = 0; q < 4; ++q)
                o[(size_t)q * Ndim] = (float)acc[mi][fj][q] * sc + bb;
        }
    }
}

// ============================================================================
// fallback 128x128 kernel (only used if workspace is too small)
// ============================================================================
template <bool AQ>
__global__ __launch_bounds__(256)
void k_gemm(const int8_t* __restrict__ Aq, const float* __restrict__ Xf,
            const int* __restrict__ W32,
            const float* __restrict__ wscale, const float* __restrict__ asc,
            const float* __restrict__ bias, float* __restrict__ out) {
    constexpr int BM = 128, BN = 128, BK = 64;
    constexpr int KT = Kdim / BK;
    __shared__ __align__(16) int8_t As[2][BM * BK];
    __shared__ __align__(16) int8_t Bs[2][BN * BK];

    const int tid  = threadIdx.x;
    const int lane = tid & 63;
    const int wid  = tid >> 6;
    const int wm = wid >> 1, wn = wid & 1;
    const int lrow = lane & 15, kgrp = lane >> 4;

    const int cpx = gridDim.x >> 3;
    const int swz = ((int)blockIdx.x & 7) * cpx + ((int)blockIdx.x >> 3);
    const int mt = swz & (Mdim / BM - 1);
    const int nt = swz / (Mdim / BM);
    const int m0 = mt * BM, n0 = nt * BN;

    const float ascale = *asc;
    const float inv = 1.0f / ascale;

    v4i acc[4][4];
#pragma unroll
    for (int i = 0; i < 4; ++i)
#pragma unroll
        for (int j = 0; j < 4; ++j) acc[i][j] = (v4i){0, 0, 0, 0};

    auto stage = [&](int buf, int kt) {
        const int k0 = kt * BK;
        if constexpr (AQ) {
            int8_t* ldsp = &As[buf][wid << 10];
            const int8_t* g = Aq + (size_t)(m0 + (tid >> 2)) * Kdim + k0 + ((tid & 3) << 4);
            __builtin_amdgcn_global_load_lds((const GAS void*)g, (LAS void*)ldsp, 16, 0, 0);
            __builtin_amdgcn_global_load_lds((const GAS void*)(g + (size_t)64 * Kdim),
                                             (LAS void*)(ldsp + 4096), 16, 0, 0);
        } else {
            const int row = tid >> 1, cb = (tid & 1) << 5;
            const float4* src = (const float4*)(Xf + (size_t)(m0 + row) * Kdim + k0 + cb);
            int t[8];
#pragma unroll
            for (int j = 0; j < 8; ++j) {
                float4 f = src[j];
                t[j] = pack4i8(qz(f.x, inv), qz(f.y, inv), qz(f.z, inv), qz(f.w, inv));
            }
            int4* dst = (int4*)&As[buf][row * BK + cb];
            dst[0] = make_int4(t[0], t[1], t[2], t[3]);
            dst[1] = make_int4(t[4], t[5], t[6], t[7]);
        }
        {
            const int row = tid >> 1, cb = (tid & 1) << 5;
            const int4* src = (const int4*)(W32 + (size_t)(n0 + row) * Kdim + k0 + cb);
            int t[8];
#pragma unroll
            for (int j = 0; j < 8; ++j) {
                int4 vv = src[j];
                t[j] = pack4i8(vv.x, vv.y, vv.z, vv.w);
            }
            int4* dst = (int4*)&Bs[buf][row * BK + cb];
            dst[0] = make_int4(t[0], t[1], t[2], t[3]);
            dst[1] = make_int4(t[4], t[5], t[6], t[7]);
        }
    };

    stage(0, 0);
    for (int kt = 0; kt < KT; ++kt) {
        const int cur = kt & 1;
        __syncthreads();
        if (kt + 1 < KT) stage(cur ^ 1, kt + 1);

        v4i a[4], b[4];
        const int koff = kgrp << 4;
#pragma unroll
        for (int i = 0; i < 4; ++i) {
            a[i] = *(const v4i*)&As[cur][(wm * 64 + i * 16 + lrow) * BK + koff];
            b[i] = *(const v4i*)&Bs[cur][(wn * 64 + i * 16 + lrow) * BK + koff];
        }
#pragma unroll
        for (int i = 0; i < 4; ++i)
#pragma unroll
            for (int j = 0; j < 4; ++j)
                acc[i][j] = __builtin_amdgcn_mfma_i32_16x16x64_i8(a[i], b[j], acc[i][j], 0, 0, 0);
    }

#pragma unroll
    for (int j = 0; j < 4; ++j) {
        const int col = n0 + wn * 64 + j * 16 + lrow;
        const float sc = ascale * wscale[col];
        const float bb = bias[col];
#pragma unroll
        for (int i = 0; i < 4; ++i) {
            const int r0 = m0 + wm * 64 + i * 16 + (kgrp << 2);
            float* o = out + (size_t)r0 * Ndim + col;
#pragma unroll
            for (int r = 0; r < 4; ++r)
                o[(size_t)r * Ndim] = (float)acc[i][j][r] * sc + bb;
        }
    }
}

extern "C" void kernel_launch(void* const* d_in, const int* in_sizes, int n_in,
                              void* d_out, int out_size, void* d_ws, size_t ws_size,
                              hipStream_t stream) {
    const float* x      = (const float*)d_in[0];
    const int*   w32    = (const int*)d_in[1];   // int8 values sign-extended to int32
    const float* wscale = (const float*)d_in[2];
    const float* asc    = (const float*)d_in[3];
    const float* bias   = (const float*)d_in[4];
    float* out = (float*)d_out;

    const size_t nx = (size_t)Mdim * Kdim;  // 33,554,432 B for x_int8
    const size_t nw = (size_t)Ndim * Kdim;  // 67,108,864 B for packed w_int8
    int8_t* xq = (int8_t*)d_ws;
    int8_t* wp = xq + nx;

    const bool haveX = ws_size >= nx;
    const bool haveW = ws_size >= nx + nw;

    if (haveX) k_quant_x<<<(int)(nx / 16 / 256), 256, 0, stream>>>(x, asc, xq);
    if (haveW) k_pack_w<<<(int)(nw / 16 / 256), 256, 0, stream>>>(w32, wp);

    if (haveW) {
        dim3 grid((Mdim / 256) * (Ndim / 128));  // 4096
        k_gemm_bp<<<grid, 256, 0, stream>>>(xq, wp, wscale, asc, bias, out);
    } else if (haveX) {
        dim3 grid((Mdim / 128) * (Ndim / 128));  // 8192
        k_gemm<true><<<grid, 256, 0, stream>>>(xq, x, w32, wscale, asc, bias, out);
    } else {
        dim3 grid((Mdim / 128) * (Ndim / 128));
        k_gemm<false><<<grid, 256, 0, stream>>>(xq, x, w32, wscale, asc, bias, out);
    }
}

// Round 10
// 822.625 us; speedup vs baseline: 1.1704x; 1.1704x over previous
//
#include <hip/hip_runtime.h>
#include <stdint.h>

#define GAS __attribute__((address_space(1)))
#define LAS __attribute__((address_space(3)))

typedef int v4i __attribute__((ext_vector_type(4)));

constexpr int Mdim = 8192;    // B*S = 4*2048
constexpr int Ndim = 16384;   // D_OUT
constexpr int Kdim = 4096;    // D_IN

__device__ __forceinline__ int pack4i8(int a, int b, int c, int d) {
    return (a & 255) | ((b & 255) << 8) | ((c & 255) << 16) | ((d & 255) << 24);
}

__device__ __forceinline__ int qz(float v, float inv) {
    return (int)fminf(fmaxf(rintf(v * inv), -128.0f), 127.0f);
}

// ---- pass 1: quantize x fp32 -> int8 (16 elems/thread) ----
__global__ void k_quant_x(const float* __restrict__ x, const float* __restrict__ asc,
                          int8_t* __restrict__ xq) {
    const int i = blockIdx.x * blockDim.x + threadIdx.x;
    const float inv = 1.0f / *asc;
    const float4* xv = (const float4*)x + (size_t)i * 4;
    float4 f0 = xv[0], f1 = xv[1], f2 = xv[2], f3 = xv[3];
    int4 o;
    o.x = pack4i8(qz(f0.x, inv), qz(f0.y, inv), qz(f0.z, inv), qz(f0.w, inv));
    o.y = pack4i8(qz(f1.x, inv), qz(f1.y, inv), qz(f1.z, inv), qz(f1.w, inv));
    o.z = pack4i8(qz(f2.x, inv), qz(f2.y, inv), qz(f2.z, inv), qz(f2.w, inv));
    o.w = pack4i8(qz(f3.x, inv), qz(f3.y, inv), qz(f3.z, inv), qz(f3.w, inv));
    ((int4*)xq)[i] = o;
}

// ---- pass 2: weight int32 (sign-extended int8) -> packed int8 ----
__global__ void k_conv_w(const int* __restrict__ w, int8_t* __restrict__ wq) {
    const int i = blockIdx.x * blockDim.x + threadIdx.x;
    const int4* wv = (const int4*)w + (size_t)i * 4;
    int4 a = wv[0], b = wv[1], c = wv[2], d = wv[3];
    int4 o;
    o.x = pack4i8(a.x, a.y, a.z, a.w);
    o.y = pack4i8(b.x, b.y, b.z, b.w);
    o.z = pack4i8(c.x, c.y, c.z, c.w);
    o.w = pack4i8(d.x, d.y, d.z, d.w);
    ((int4*)wq)[i] = o;
}

// ============================================================================
// pass 3 (main): 256x256, 8 waves, K-tile=128B, 2-deep dbuf (128 KiB LDS),
// 8 phases/iter, ONE barrier per phase (the de-phasing fix):
//   phase p = { ds_read frags(p) ; stage 1 region ; vmcnt(8) ; s_barrier ;
//               sched_barrier ; setprio(1) 16 MFMA setprio(0) }
//   Waves may slip <= 1 phase (bounded by the barrier chain): an early wave's
//   reads_{p+1} overlap a late wave's MFMA_p -> LDS drain (~500 cy/CU) hides
//   under the MFMA window (~653 cy/SIMD).
// Hazard ledger (verified under +-1 slip and compiler-hoist bounds; memory
// ops are fenced between consecutive sched_barrier(0)s):
//   read schedule: ph1 A-b0k0h0+B-b0k0, ph2 A-b0k0h1, ph3 A-b0k1h0+B-b0k1,
//     ph4 A-b0k1h1, ph5 A-b1k0h0+B-b1k0, ph6 A-b1k0h1, ph7 A-b1k1h0+B-b1k1,
//     ph8 A-b1k1h1.
//   stage cadence (iter j, t0=2j, t1=2j+1): ph1 stB(t1,k1) ph2 stA(t1,k1)
//     ph3 stB(t0+2,k0) ph4 stA(t0+2,k0) ph5 stB(t0+2,k1) ph6 stA(t0+2,k1)
//     ph7 stB(t1+2,k0) ph8 stA(t1+2,k0)
//   -> every region re-staged exactly 2 phases (2 barriers) after last read;
//   vmcnt(8)/phase retires stage(p-4), >=1 barrier before its first read
//   (tightest: A-b1k1 staged ph2, retired ph6, read ph7). Steady in-flight
//   8-10 loads; stage->demand ~4 phases (~4000 cy >> 900 cy HBM).
//   Tail iter: stages ph1/ph2 only; vmcnt peels VM4@ph4, VM0@ph6.
//   Swizzle identical to rounds 2-9 (verified SQ_LDS_BANK_CONFLICT == 0).
// ============================================================================
constexpr int NT    = Kdim / 128;  // 32 K-tiles
constexpr int NITER = NT / 2;      // 16

#define VM8  asm volatile("s_waitcnt vmcnt(8)"  ::: "memory")
#define VM4  asm volatile("s_waitcnt vmcnt(4)"  ::: "memory")
#define VM0  asm volatile("s_waitcnt vmcnt(0)"  ::: "memory")

// one phase: reads for THIS phase's MFMA, one stage call, vmcnt, single
// barrier, MFMA cluster. bfr persists across the odd->even phase pair.
#define PH(ABASE, READB, AROW, ACC0, STAGE_STMT, VM_STMT)                      \
  {                                                                            \
    if (READB) {                                                               \
      _Pragma("unroll") for (int f = 0; f < 4; ++f)                            \
          bfr[f] = *(const v4i*)(lds + (ABASE) + 32768 + browb + f * 1024);    \
    }                                                                          \
    _Pragma("unroll") for (int f = 0; f < 4; ++f)                              \
        afr[f] = *(const v4i*)(lds + (ABASE) + (AROW) + f * 1024);             \
    STAGE_STMT;                                                                \
    VM_STMT;                                                                   \
    __builtin_amdgcn_s_barrier();                                              \
    __builtin_amdgcn_sched_barrier(0);                                         \
    __builtin_amdgcn_s_setprio(1);                                             \
    _Pragma("unroll") for (int fi = 0; fi < 4; ++fi)                           \
        _Pragma("unroll") for (int fj = 0; fj < 4; ++fj)                       \
            acc[(ACC0) + fi][fj] = __builtin_amdgcn_mfma_i32_16x16x64_i8(      \
                afr[fi], bfr[fj], acc[(ACC0) + fi][fj], 0, 0, 0);              \
    __builtin_amdgcn_s_setprio(0);                                             \
  }

__global__ __launch_bounds__(512, 2)
void k_gemm256(const int8_t* __restrict__ Aq, const int8_t* __restrict__ Bq,
               const float* __restrict__ wscale, const float* __restrict__ asc,
               const float* __restrict__ bias, float* __restrict__ out) {
    __shared__ __align__(16) int8_t lds[131072];
    const int tid = threadIdx.x, lane = tid & 63, w = tid >> 6;
    const int wm = w >> 2, wn = w & 3;              // 2M x 4N wave grid
    const int lrow = lane & 15, kgrp = lane >> 4;

    const int bid = blockIdx.x;                     // grid = 2048, %8 == 0
    const int swz = ((bid & 7) << 8) | (bid >> 3);  // bijective XCD swizzle
    const int mt = swz & 31, nt = swz >> 5;         // m fastest: share B panel
    const int m0 = mt << 8, n0 = nt << 8;

    // ---- staging geometry (verified 0-conflict, rounds 2-9) ----
    const int srow = tid >> 2;                      // row within 128-row unit
    const int scol = (((tid & 3) ^ ((tid >> 3) & 3)) << 4);
    const int8_t* rowA0 = Aq + (size_t)(m0 + srow) * Kdim + scol;
    const int8_t* rowB0 = Bq + (size_t)(n0 + srow) * Kdim + scol;
    const size_t rb1off = (size_t)128 * Kdim;
    const int dstoff = w << 10;                     // + HW lane*16

    auto stA = [&](int t, int ks) {
        int8_t* d = lds + ((t & 1) << 16) + (ks << 14) + dstoff;
        const int8_t* s = rowA0 + t * 128 + ks * 64;
        __builtin_amdgcn_global_load_lds((const GAS void*)s, (LAS void*)d, 16, 0, 0);
        __builtin_amdgcn_global_load_lds((const GAS void*)(s + rb1off), (LAS void*)(d + 8192), 16, 0, 0);
    };
    auto stB = [&](int t, int ks) {
        int8_t* d = lds + ((t & 1) << 16) + 32768 + (ks << 14) + dstoff;
        const int8_t* s = rowB0 + t * 128 + ks * 64;
        __builtin_amdgcn_global_load_lds((const GAS void*)s, (LAS void*)d, 16, 0, 0);
        __builtin_amdgcn_global_load_lds((const GAS void*)(s + rb1off), (LAS void*)(d + 8192), 16, 0, 0);
    };

    // ---- read-side addressing (verified conflict-free swizzle) ----
    const int kc = (kgrp ^ ((lrow >> 1) & 3)) << 4;
    const int arow0 = ((wm << 7) + lrow) * 64 + kc;        // h0 rows
    const int arow1 = ((wm << 7) + 64 + lrow) * 64 + kc;   // h1 rows
    const int browb = ((wn << 6) + lrow) * 64 + kc;

    v4i acc[8][4];
#pragma unroll
    for (int i = 0; i < 8; ++i)
#pragma unroll
        for (int j = 0; j < 4; ++j) acc[i][j] = (v4i){0, 0, 0, 0};

    v4i afr[4], bfr[4];

    // prologue: stage (b0k0),(b0k1),(b1k0) A+B = 12 loads; drain; barrier.
    stB(0, 0); stA(0, 0); stB(0, 1); stA(0, 1); stB(1, 0); stA(1, 0);
    VM0;
    __builtin_amdgcn_s_barrier();

    for (int j = 0; j < NITER - 1; ++j) {
        const int t0 = 2 * j, t1 = 2 * j + 1;
        PH(0,     true,  arow0, 0, stB(t1, 1),     VM8)   // ph1
        PH(0,     false, arow1, 4, stA(t1, 1),     VM8)   // ph2
        PH(16384, true,  arow0, 0, stB(t0 + 2, 0), VM8)   // ph3
        PH(16384, false, arow1, 4, stA(t0 + 2, 0), VM8)   // ph4
        PH(65536, true,  arow0, 0, stB(t0 + 2, 1), VM8)   // ph5
        PH(65536, false, arow1, 4, stA(t0 + 2, 1), VM8)   // ph6
        PH(81920, true,  arow0, 0, stB(t1 + 2, 0), VM8)   // ph7
        PH(81920, false, arow1, 4, stA(t1 + 2, 0), VM8)   // ph8
    }

    // tail iter (tiles 30,31): stages ph1/ph2 only; vmcnt peels 4/0.
    {
        PH(0,     true,  arow0, 0, stB(31, 1), VM8)       // ph1
        PH(0,     false, arow1, 4, stA(31, 1), VM8)       // ph2
        PH(16384, true,  arow0, 0, (void)0,    (void)0)   // ph3
        PH(16384, false, arow1, 4, (void)0,    VM4)       // ph4
        PH(65536, true,  arow0, 0, (void)0,    (void)0)   // ph5
        PH(65536, false, arow1, 4, (void)0,    VM0)       // ph6
        PH(81920, true,  arow0, 0, (void)0,    (void)0)   // ph7
        PH(81920, false, arow1, 4, (void)0,    (void)0)   // ph8
    }

    // epilogue: y = i32 * (act_scale * wscale[n]) + bias[n]
    const float ascale = *asc;
#pragma unroll
    for (int fj = 0; fj < 4; ++fj) {
        const int col = n0 + (wn << 6) + fj * 16 + lrow;
        const float sc = ascale * wscale[col];
        const float bb = bias[col];
#pragma unroll
        for (int mi = 0; mi < 8; ++mi) {
            const int r0 = m0 + (wm << 7) + mi * 16 + (kgrp << 2);
            float* o = out + (size_t)r0 * Ndim + col;
#pragma unroll
            for (int q = 0; q < 4; ++q)
                o[(size_t)q * Ndim] = (float)acc[mi][fj][q] * sc + bb;
        }
    }
}

// ============================================================================
// fallback 128x128 kernel (only used if workspace is too small)
// ============================================================================
template <bool AQ, bool BQ>
__global__ __launch_bounds__(256)
void k_gemm(const int8_t* __restrict__ Aq, const float* __restrict__ Xf,
            const int8_t* __restrict__ Bq, const int* __restrict__ W32,
            const float* __restrict__ wscale, const float* __restrict__ asc,
            const float* __restrict__ bias, float* __restrict__ out) {
    constexpr int BM = 128, BN = 128, BK = 64;
    constexpr int KT = Kdim / BK;
    __shared__ __align__(16) int8_t As[2][BM * BK];
    __shared__ __align__(16) int8_t Bs[2][BN * BK];

    const int tid  = threadIdx.x;
    const int lane = tid & 63;
    const int wid  = tid >> 6;
    const int wm = wid >> 1, wn = wid & 1;
    const int lrow = lane & 15, kgrp = lane >> 4;

    const int cpx = gridDim.x >> 3;
    const int swz = ((int)blockIdx.x & 7) * cpx + ((int)blockIdx.x >> 3);
    const int mt = swz & (Mdim / BM - 1);
    const int nt = swz / (Mdim / BM);
    const int m0 = mt * BM, n0 = nt * BN;

    const float ascale = *asc;
    const float inv = 1.0f / ascale;

    v4i acc[4][4];
#pragma unroll
    for (int i = 0; i < 4; ++i)
#pragma unroll
        for (int j = 0; j < 4; ++j) acc[i][j] = (v4i){0, 0, 0, 0};

    auto stage = [&](int buf, int kt) {
        const int k0 = kt * BK;
        if constexpr (AQ) {
            int8_t* ldsp = &As[buf][wid << 10];
            const int8_t* g = Aq + (size_t)(m0 + (tid >> 2)) * Kdim + k0 + ((tid & 3) << 4);
            __builtin_amdgcn_global_load_lds((const GAS void*)g, (LAS void*)ldsp, 16, 0, 0);
            __builtin_amdgcn_global_load_lds((const GAS void*)(g + (size_t)64 * Kdim),
                                             (LAS void*)(ldsp + 4096), 16, 0, 0);
        } else {
            const int row = tid >> 1, cb = (tid & 1) << 5;
            const float4* src = (const float4*)(Xf + (size_t)(m0 + row) * Kdim + k0 + cb);
            int t[8];
#pragma unroll
            for (int j = 0; j < 8; ++j) {
                float4 f = src[j];
                t[j] = pack4i8(qz(f.x, inv), qz(f.y, inv), qz(f.z, inv), qz(f.w, inv));
            }
            int4* dst = (int4*)&As[buf][row * BK + cb];
            dst[0] = make_int4(t[0], t[1], t[2], t[3]);
            dst[1] = make_int4(t[4], t[5], t[6], t[7]);
        }
        if constexpr (BQ) {
            int8_t* ldsp = &Bs[buf][wid << 10];
            const int8_t* g = Bq + (size_t)(n0 + (tid >> 2)) * Kdim + k0 + ((tid & 3) << 4);
            __builtin_amdgcn_global_load_lds((const GAS void*)g, (LAS void*)ldsp, 16, 0, 0);
            __builtin_amdgcn_global_load_lds((const GAS void*)(g + (size_t)64 * Kdim),
                                             (LAS void*)(ldsp + 4096), 16, 0, 0);
        } else {
            const int row = tid >> 1, cb = (tid & 1) << 5;
            const int4* src = (const int4*)(W32 + (size_t)(n0 + row) * Kdim + k0 + cb);
            int t[8];
#pragma unroll
            for (int j = 0; j < 8; ++j) {
                int4 vv = src[j];
                t[j] = pack4i8(vv.x, vv.y, vv.z, vv.w);
            }
            int4* dst = (int4*)&Bs[buf][row * BK + cb];
            dst[0] = make_int4(t[0], t[1], t[2], t[3]);
            dst[1] = make_int4(t[4], t[5], t[6], t[7]);
        }
    };

    stage(0, 0);
    for (int kt = 0; kt < KT; ++kt) {
        const int cur = kt & 1;
        __syncthreads();
        if (kt + 1 < KT) stage(cur ^ 1, kt + 1);

        v4i a[4], b[4];
        const int koff = kgrp << 4;
#pragma unroll
        for (int i = 0; i < 4; ++i) {
            a[i] = *(const v4i*)&As[cur][(wm * 64 + i * 16 + lrow) * BK + koff];
            b[i] = *(const v4i*)&Bs[cur][(wn * 64 + i * 16 + lrow) * BK + koff];
        }
#pragma unroll
        for (int i = 0; i < 4; ++i)
#pragma unroll
            for (int j = 0; j < 4; ++j)
                acc[i][j] = __builtin_amdgcn_mfma_i32_16x16x64_i8(a[i], b[j], acc[i][j], 0, 0, 0);
    }

#pragma unroll
    for (int j = 0; j < 4; ++j) {
        const int col = n0 + wn * 64 + j * 16 + lrow;
        const float sc = ascale * wscale[col];
        const float bb = bias[col];
#pragma unroll
        for (int i = 0; i < 4; ++i) {
            const int r0 = m0 + wm * 64 + i * 16 + (kgrp << 2);
            float* o = out + (size_t)r0 * Ndim + col;
#pragma unroll
            for (int r = 0; r < 4; ++r)
                o[(size_t)r * Ndim] = (float)acc[i][j][r] * sc + bb;
        }
    }
}

extern "C" void kernel_launch(void* const* d_in, const int* in_sizes, int n_in,
                              void* d_out, int out_size, void* d_ws, size_t ws_size,
                              hipStream_t stream) {
    const float* x      = (const float*)d_in[0];
    const int*   w32    = (const int*)d_in[1];   // int8 values sign-extended to int32
    const float* wscale = (const float*)d_in[2];
    const float* asc    = (const float*)d_in[3];
    const float* bias   = (const float*)d_in[4];
    float* out = (float*)d_out;

    const size_t nx = (size_t)Mdim * Kdim;  // 33,554,432 B for x_int8
    const size_t nw = (size_t)Ndim * Kdim;  // 67,108,864 B for w_int8
    int8_t* xq = (int8_t*)d_ws;
    int8_t* wq = xq + nx;

    const bool haveX = ws_size >= nx;
    const bool haveW = ws_size >= nx + nw;

    if (haveX) k_quant_x<<<(int)(nx / 16 / 256), 256, 0, stream>>>(x, asc, xq);
    if (haveW) k_conv_w<<<(int)(nw / 16 / 256), 256, 0, stream>>>(w32, wq);

    if (haveW) {
        dim3 grid((Mdim / 256) * (Ndim / 256));  // 2048
        k_gemm256<<<grid, 512, 0, stream>>>(xq, wq, wscale, asc, bias, out);
    } else if (haveX) {
        dim3 grid((Mdim / 128) * (Ndim / 128));  // 8192
        k_gemm<true, false><<<grid, 256, 0, stream>>>(xq, x, wq, w32, wscale, asc, bias, out);
    } else {
        dim3 grid((Mdim / 128) * (Ndim / 128));
        k_gemm<false, false><<<grid, 256, 0, stream>>>(xq, x, wq, w32, wscale, asc, bias, out);
    }
}